// Round 13
// baseline (52.550 us; speedup 1.0000x reference)
//
#include <hip/hip_runtime.h>
#include <hip/hip_bf16.h>

#define SEQ    2048
#define NHEAD  16
#define RPH    512          // rows per head = B*D
#define BM     64           // rows per block
#define BK     64
#define NTH    256          // 4 waves: (tile-half tb = wv>>1, row-half r = wv&1)

#define WSTRIDE 2184        // elems per wrev copy; 2184 % 64 == 8 (uniform slots)
#define ABUF_E  4096        // elems per A buffer (64 rows x 64 cols bf16)
#define WCOP_E  (2 * ABUF_E)                     // wcop after the two A buffers
#define TOT_E   (WCOP_E + 8 * WSTRIDE + 128)     // +128 pad: tb0 tail refills
// wbase staging (guard 0..7, data 8..2055, zero pad 2056..2215) aliases abufs

typedef float  f32x4  __attribute__((ext_vector_type(4)));
typedef __bf16 bf16x8 __attribute__((ext_vector_type(8)));

struct PF { float4 v0, v1, v2, v3; };

__device__ __forceinline__ unsigned f2bf(float f) {
    union { __hip_bfloat16 h; unsigned short u; } cv;
    cv.h = __float2bfloat16(f);
    return (unsigned)cv.u;
}

__device__ __forceinline__ uint4 pack8u(float4 a, float4 b) {
    union { bf16x8 v; uint4 u; } r;
    r.v[0] = (__bf16)a.x; r.v[1] = (__bf16)a.y;
    r.v[2] = (__bf16)a.z; r.v[3] = (__bf16)a.w;
    r.v[4] = (__bf16)b.x; r.v[5] = (__bf16)b.y;
    r.v[6] = (__bf16)b.z; r.v[7] = (__bf16)b.w;
    return r.u;
}

#define MFMA16(a, b, c) __builtin_amdgcn_mfma_f32_16x16x32_bf16((a), (b), (c), 0, 0, 0)

// Load this lane's 1 staged row x 16 cols fp32 of chunk CH (wave stages 16
// rows: lane>>2 = row-in-16, (lane&3)*16 = col base).
#define LOADPF(P, CH)                                                         \
  { const float* g_ = Xp + (size_t)(CH) * BK;                                 \
    P.v0 = *(const float4*)g_;                                                \
    P.v1 = *(const float4*)(g_ + 4);                                          \
    P.v2 = *(const float4*)(g_ + 8);                                          \
    P.v3 = *(const float4*)(g_ + 12); }

// Pack+write this wave's 16 staged rows into shared buffer AB (XOR-swizzled).
#define WRITEA(AB, P)                                                         \
  { *(uint4*)((AB) + wb0) = pack8u(P.v0, P.v1);                               \
    *(uint4*)((AB) + wb1) = pack8u(P.v2, P.v3); }

// Load 4 window words (16 elems apart) into slots S0..S3 of bw[16].
#define WINLOAD4(CH, OFFE, S0, S1, S2, S3)                                    \
  { const unsigned short* bq_ = wcB + 64 * (CH) + (OFFE);                     \
    bw[S0] = *(const bf16x8*)(bq_);                                           \
    bw[S1] = *(const bf16x8*)(bq_ + 16);                                      \
    bw[S2] = *(const bf16x8*)(bq_ + 32);                                      \
    bw[S3] = *(const bf16x8*)(bq_ + 48); }

// One K=32 step: A frags from shared LDS buf ABC, B words from circular bw
// at slot (P8 + BASE - c) & 15 (all compile-time constants).
#define KSTEPW(ABC, KS, P8, BASE)                                             \
  { const int kb_ = (64 * (KS) + kq16) ^ swz;                                 \
    bf16x8 af0 = *(const bf16x8*)((ABC) + Arow0 + kb_);                       \
    bf16x8 af1 = *(const bf16x8*)((ABC) + Arow1 + kb_);                       \
    acc[0][0] = MFMA16(af0, bw[((P8)+(BASE)-0)&15], acc[0][0]);               \
    acc[1][0] = MFMA16(af1, bw[((P8)+(BASE)-0)&15], acc[1][0]);               \
    acc[0][1] = MFMA16(af0, bw[((P8)+(BASE)-1)&15], acc[0][1]);               \
    acc[1][1] = MFMA16(af1, bw[((P8)+(BASE)-1)&15], acc[1][1]);               \
    acc[0][2] = MFMA16(af0, bw[((P8)+(BASE)-2)&15], acc[0][2]);               \
    acc[1][2] = MFMA16(af1, bw[((P8)+(BASE)-2)&15], acc[1][2]);               \
    acc[0][3] = MFMA16(af0, bw[((P8)+(BASE)-3)&15], acc[0][3]);               \
    acc[1][3] = MFMA16(af1, bw[((P8)+(BASE)-3)&15], acc[1][3]);               \
    acc[0][4] = MFMA16(af0, bw[((P8)+(BASE)-4)&15], acc[0][4]);               \
    acc[1][4] = MFMA16(af1, bw[((P8)+(BASE)-4)&15], acc[1][4]);               \
    acc[0][5] = MFMA16(af0, bw[((P8)+(BASE)-5)&15], acc[0][5]);               \
    acc[1][5] = MFMA16(af1, bw[((P8)+(BASE)-5)&15], acc[1][5]);               \
    acc[0][6] = MFMA16(af0, bw[((P8)+(BASE)-6)&15], acc[0][6]);               \
    acc[1][6] = MFMA16(af1, bw[((P8)+(BASE)-6)&15], acc[1][6]);               \
    acc[0][7] = MFMA16(af0, bw[((P8)+(BASE)-7)&15], acc[0][7]);               \
    acc[1][7] = MFMA16(af1, bw[((P8)+(BASE)-7)&15], acc[1][7]); }

// One pair (chunks ch, ch+1), one barrier per chunk (cross-wave A sharing).
// Entry state: ab0 holds A(ch) (visible), pfB = x(ch+1), pfA = x(ch+2).
// WINLOAD4s sit AFTER the barriers: wcop is read-only, so they need no
// ordering, and the lgkmcnt(0) drain no longer waits on them.
#define PAIRBODY(P8)                                                          \
  {                                                                           \
    WRITEA(ab1, pfB);                      /* stage A(ch+1)              */   \
    if (ch + 3 < nch) LOADPF(pfB, ch + 3);                                    \
    if (ch < nchw) {                                                          \
      __builtin_amdgcn_s_setprio(1);                                          \
      KSTEPW(ab0, 0, P8, 7);                                                  \
      KSTEPW(ab0, 1, P8, 9);                                                  \
      __builtin_amdgcn_s_setprio(0);                                          \
    }                                                                         \
    asm volatile("s_waitcnt lgkmcnt(0)\n\ts_barrier" ::: "memory");           \
    if (ch + 2 < nch)                                                         \
        WINLOAD4(ch, 112, ((P8)+14)&15, ((P8)+15)&15,                         \
                 ((P8)+16)&15, ((P8)+17)&15);                                 \
    if (ch + 2 < nch) WRITEA(ab0, pfA);    /* stage A(ch+2)              */   \
    if (ch + 4 < nch) LOADPF(pfA, ch + 4);                                    \
    if (ch + 1 < nchw) {                                                      \
      __builtin_amdgcn_s_setprio(1);                                          \
      KSTEPW(ab1, 0, P8, 11);                                                 \
      KSTEPW(ab1, 1, P8, 13);                                                 \
      __builtin_amdgcn_s_setprio(0);                                          \
    }                                                                         \
    asm volatile("s_waitcnt lgkmcnt(0)\n\ts_barrier" ::: "memory");           \
    if (ch + 2 < nch)                                                         \
        WINLOAD4(ch, 176, ((P8)+18)&15, ((P8)+19)&15,                         \
                 ((P8)+20)&15, ((P8)+21)&15);                                 \
  }

__global__ __launch_bounds__(NTH, 3) void mixer_kernel(
    const float* __restrict__ x, const float* __restrict__ wgt,
    const float* __restrict__ bias, float* __restrict__ out)
{
    __shared__ unsigned short smem[TOT_E] __attribute__((aligned(16)));
    char* ab0 = (char*)smem;                    // A buffer 0 (even chunks)
    char* ab1 = (char*)smem + ABUF_E * 2;       // A buffer 1 (odd chunks)
    unsigned short* wc = smem + WCOP_E;         // 8 shifted reversed-w copies

    const int tid  = threadIdx.x;
    const int lane = tid & 63;
    const int wv   = tid >> 6;                  // 0..3
    const int r    = wv & 1;                    // row half (32 rows each)
    const int tb   = wv >> 1;                   // tile half: ct = 2j + tb

    // ---- block decode: 1024 blocks, adjacent-ct pairs, heavy-first LPT ----
    const int bid  = blockIdx.x;               // 0..1023
    const int m    = (bid & 7) + 8 * ((bid >> 3) & 1);
    const int rt   = (bid >> 4) & 7;           // row tile 0..7 (64 rows)
    const int j    = 7 - (bid >> 7);           // pair id; j=7 (K=2048) first
    const int nch  = 4 * j + 4;                // shared K sweep chunks (of 64)
    const int nchw = nch - 2 + 2 * tb;         // this wave's MFMA extent

    const float* Xb = x   + (size_t)(m * RPH + rt * BM) * SEQ;
    float*       Ob = out + (size_t)(m * RPH + rt * BM) * SEQ;
    const float* wr = wgt  + m * SEQ;
    const float* br = bias + m * SEQ;

    // ---- staging map: wave stages 16 rows = [16*wv, 16*wv+16) ----
    const int srow = 16 * wv + (lane >> 2);
    const int colq = lane & 3;                 // 16-fp32 column quarter
    const int wsw  = (srow & 7) << 4;
    const int wb0  = srow * 128 + ((colq * 32) ^ wsw);
    const int wb1  = srow * 128 + ((colq * 32 + 16) ^ wsw);
    const float* Xp = Xb + (size_t)srow * SEQ + colq * 16;

    // ---- issue chunk-0/1 prefetch immediately (hides under prologue) ----
    PF pfA, pfB;
    LOADPF(pfA, 0);
    LOADPF(pfB, 1);

    // ---- phase 1: reversed bf16 weights into abuf-alias ----
    {
        const int t8 = tid * 8;                // 0..2040
        const float* g = wr + (2040 - t8);
        float4 lo = *(const float4*)g;
        float4 hi = *(const float4*)(g + 4);
        uint4 v;
        v.x = f2bf(hi.w) | (f2bf(hi.z) << 16);
        v.y = f2bf(hi.y) | (f2bf(hi.x) << 16);
        v.z = f2bf(lo.w) | (f2bf(lo.z) << 16);
        v.w = f2bf(lo.y) | (f2bf(lo.x) << 16);
        *(uint4*)(smem + 8 + t8) = v;
        if (tid < 21) {                        // guard (8) + pad (160)
            uint4 z = {0u, 0u, 0u, 0u};
            unsigned short* dst = (tid == 0) ? smem
                                 : smem + 8 + 2048 + (tid - 1) * 8;
            *(uint4*)dst = z;
        }
    }
    __syncthreads();

    // ---- phase 2: 8 shifted copies, vectorized: copy_c[i] = wbase[i-c] ----
    #pragma unroll
    for (int c = 0; c < 8; ++c) {
        for (int grp = tid; grp < WSTRIDE / 8; grp += NTH) {
            const int i = grp * 8;
            uint4 g0 = *(const uint4*)(smem + 8 + i - 8);
            uint4 g1 = *(const uint4*)(smem + 8 + i);
            unsigned d[9] = {g0.x, g0.y, g0.z, g0.w,
                             g1.x, g1.y, g1.z, g1.w, 0u};
            const int qd = (16 - 2 * c) >> 2;
            uint4 o;
            if (c & 1) {
                o.x = (d[qd]     >> 16) | (d[qd + 1] << 16);
                o.y = (d[qd + 1] >> 16) | (d[qd + 2] << 16);
                o.z = (d[qd + 2] >> 16) | (d[qd + 3] << 16);
                o.w = (d[qd + 3] >> 16) | (d[qd + 4] << 16);
            } else {
                o.x = d[qd];     o.y = d[qd + 1];
                o.z = d[qd + 2]; o.w = d[qd + 3];
            }
            *(uint4*)(wc + c * WSTRIDE + i) = o;
        }
    }
    __syncthreads();   // wcop ready; wbase alias (ab0/ab1) free to overwrite

    // ---- per-lane MFMA constants ----
    const int col_low = lane & 15;
    const int kq      = lane >> 4;
    const int kq16    = kq * 16;
    const int swz     = (col_low & 7) << 4;
    const int rbw     = 32 * r;                // wave's output rows
    const int t0w     = 256 * j + 128 * tb;    // wave's tile col base
    const int cpy     = (col_low + 1) & 7;     // alignment class -> copy id
    const int BcBase  = cpy * WSTRIDE + cpy + 2047 - col_low + 8 * kq;
    const int Arow0   = (rbw      + col_low) * 128;
    const int Arow1   = (rbw + 16 + col_low) * 128;
    const unsigned short* wcB = wc + (BcBase - t0w);

    // ---- seed: stage chunk 0 (shared), load window, advance pfA to ch2 ----
    WRITEA(ab0, pfA);
    LOADPF(pfA, 2);                            // nch >= 4 always

    bf16x8 bw[16];
    {
        const unsigned short* bq_ = wcB - 112; // words -7..6 -> slots 0..13
        #pragma unroll
        for (int i = 0; i < 14; ++i)
            bw[i] = *(const bf16x8*)(bq_ + 16 * i);
    }
    __syncthreads();                           // ab0(chunk 0) visible to all

    f32x4 acc[2][8] = {};
    int ch = 0;
    for (;;) {
        PAIRBODY(0);
        ch += 2; if (ch >= nch) break;
        PAIRBODY(8);
        ch += 2; if (ch >= nch) break;
    }

    // ---- epilogue: C/D layout col=lane&15, row=(lane>>4)*4+reg ----
    #pragma unroll
    for (int c = 0; c < 8; ++c) {
        const int colg = t0w + 16 * c + col_low;
        const float bv = br[colg];
        #pragma unroll
        for (int a = 0; a < 2; ++a) {
            const int rowl = rbw + 16 * a + 4 * kq;
            #pragma unroll
            for (int rr = 0; rr < 4; ++rr)
                Ob[(size_t)(rowl + rr) * SEQ + colg] = acc[a][c][rr] + bv;
        }
    }
}

extern "C" void kernel_launch(void* const* d_in, const int* in_sizes, int n_in,
                              void* d_out, int out_size, void* d_ws, size_t ws_size,
                              hipStream_t stream) {
    const float* x  = (const float*)d_in[0];
    const float* w  = (const float*)d_in[1];
    const float* bs = (const float*)d_in[2];
    float* out = (float*)d_out;
    dim3 grid(1024);   // 16 heads x 8 row tiles x 8 adjacent-ct pairs (LPT)
    dim3 block(NTH);
    hipLaunchKernelGGL(mixer_kernel, grid, block, 0, stream, x, w, bs, out);
}

// Round 14
// 43.949 us; speedup vs baseline: 1.1957x; 1.1957x over previous
//
#include <hip/hip_runtime.h>
#include <hip/hip_bf16.h>

#define SEQ    2048
#define NHEAD  16
#define RPH    512          // rows per head = B*D
#define BM     128
#define BK     64
#define NTH    512          // 8 waves: (tile-half tb = wv>>2, row-oct r = wv&3)

#define WSTRIDE 2184        // elems per wrev copy; 2184 % 64 == 8 (uniform slots)
#define ABUF_E  8192        // elems per A buffer (128 rows x 64 cols bf16)
#define WCOP_E  (2 * ABUF_E)                     // wcop after the two A buffers
#define TOT_E   (WCOP_E + 8 * WSTRIDE + 128)     // +128 pad: tail window reads
// wbase staging (guard 0..7, data 8..2055, zero pad 2056..2215) aliases abuf0

typedef float  f32x4  __attribute__((ext_vector_type(4)));
typedef __bf16 bf16x8 __attribute__((ext_vector_type(8)));

struct PF { float4 v0, v1, v2, v3; };

__device__ __forceinline__ unsigned f2bf(float f) {
    union { __hip_bfloat16 h; unsigned short u; } cv;
    cv.h = __float2bfloat16(f);
    return (unsigned)cv.u;
}

__device__ __forceinline__ uint4 pack8u(float4 a, float4 b) {
    union { bf16x8 v; uint4 u; } r;
    r.v[0] = (__bf16)a.x; r.v[1] = (__bf16)a.y;
    r.v[2] = (__bf16)a.z; r.v[3] = (__bf16)a.w;
    r.v[4] = (__bf16)b.x; r.v[5] = (__bf16)b.y;
    r.v[6] = (__bf16)b.z; r.v[7] = (__bf16)b.w;
    return r.u;
}

#define MFMA16(a, b, c) __builtin_amdgcn_mfma_f32_16x16x32_bf16((a), (b), (c), 0, 0, 0)

// Load this lane's 1 staged row x 16 cols fp32 of chunk CH.
#define LOADPF(P, CH)                                                         \
  { const float* g_ = Xp + (size_t)(CH) * BK;                                 \
    P.v0 = *(const float4*)g_;                                                \
    P.v1 = *(const float4*)(g_ + 4);                                          \
    P.v2 = *(const float4*)(g_ + 8);                                          \
    P.v3 = *(const float4*)(g_ + 12); }

// Pack+write this wave's 16 staged rows into shared buffer AB (XOR-swizzled).
#define WRITEA(AB, P)                                                         \
  { *(uint4*)((AB) + wb0) = pack8u(P.v0, P.v1);                               \
    *(uint4*)((AB) + wb1) = pack8u(P.v2, P.v3); }

// k-step 0 of chunk: A frag at k 0..31, B word (7-c) in slot 7-c.
#define KSTEP0(ABC)                                                           \
  { const int kb_ = kq16 ^ swz;                                               \
    bf16x8 af0 = *(const bf16x8*)((ABC) + Arow0 + kb_);                       \
    bf16x8 af1 = *(const bf16x8*)((ABC) + Arow1 + kb_);                       \
    acc[0][0] = MFMA16(af0, bw[7], acc[0][0]);                                \
    acc[1][0] = MFMA16(af1, bw[7], acc[1][0]);                                \
    acc[0][1] = MFMA16(af0, bw[6], acc[0][1]);                                \
    acc[1][1] = MFMA16(af1, bw[6], acc[1][1]);                                \
    acc[0][2] = MFMA16(af0, bw[5], acc[0][2]);                                \
    acc[1][2] = MFMA16(af1, bw[5], acc[1][2]);                                \
    acc[0][3] = MFMA16(af0, bw[4], acc[0][3]);                                \
    acc[1][3] = MFMA16(af1, bw[4], acc[1][3]);                                \
    acc[0][4] = MFMA16(af0, bw[3], acc[0][4]);                                \
    acc[1][4] = MFMA16(af1, bw[3], acc[1][4]);                                \
    acc[0][5] = MFMA16(af0, bw[2], acc[0][5]);                                \
    acc[1][5] = MFMA16(af1, bw[2], acc[1][5]);                                \
    acc[0][6] = MFMA16(af0, bw[1], acc[0][6]);                                \
    acc[1][6] = MFMA16(af1, bw[1], acc[1][6]);                                \
    acc[0][7] = MFMA16(af0, bw[0], acc[0][7]);                                \
    acc[1][7] = MFMA16(af1, bw[0], acc[1][7]); }

// k-step 1: A frag at k 32..63, B word (9-c): words 8,9 were reloaded into
// slots 0,1 after KSTEP0. Old-word MFMAs (c>=2) emitted first to give the
// two fresh loads latency cover.
#define KSTEP1(ABC)                                                           \
  { const int kb_ = (64 + kq16) ^ swz;                                        \
    bf16x8 af0 = *(const bf16x8*)((ABC) + Arow0 + kb_);                       \
    bf16x8 af1 = *(const bf16x8*)((ABC) + Arow1 + kb_);                       \
    acc[0][7] = MFMA16(af0, bw[2], acc[0][7]);                                \
    acc[1][7] = MFMA16(af1, bw[2], acc[1][7]);                                \
    acc[0][6] = MFMA16(af0, bw[3], acc[0][6]);                                \
    acc[1][6] = MFMA16(af1, bw[3], acc[1][6]);                                \
    acc[0][5] = MFMA16(af0, bw[4], acc[0][5]);                                \
    acc[1][5] = MFMA16(af1, bw[4], acc[1][5]);                                \
    acc[0][4] = MFMA16(af0, bw[5], acc[0][4]);                                \
    acc[1][4] = MFMA16(af1, bw[5], acc[1][4]);                                \
    acc[0][3] = MFMA16(af0, bw[6], acc[0][3]);                                \
    acc[1][3] = MFMA16(af1, bw[6], acc[1][3]);                                \
    acc[0][2] = MFMA16(af0, bw[7], acc[0][2]);                                \
    acc[1][2] = MFMA16(af1, bw[7], acc[1][2]);                                \
    acc[0][1] = MFMA16(af0, bw[0], acc[0][1]);                                \
    acc[1][1] = MFMA16(af1, bw[0], acc[1][1]);                                \
    acc[0][0] = MFMA16(af0, bw[1], acc[0][0]);                                \
    acc[1][0] = MFMA16(af1, bw[1], acc[1][0]); }

// One chunk CH, one barrier (cross-wave A sharing). Entry: ABC holds A(CH)
// visible to all waves, pf = x(CH+1). Exit: ABN = A(CH+1) visible, pf = x(CH+2).
// B window is flat per chunk: word i (i=0..9) at elems wcB + 64*CH + 16*(i-7),
// used by ks0 at slot 7-c, ks1 at word 9-c (slots 0,1 recycled for words 8,9).
#define CHUNKBODY(CH, ABC, ABN)                                               \
  {                                                                           \
    WRITEA(ABN, pf);                       /* stage A(CH+1) (tail: inert) */  \
    if ((CH) + 2 < nch) LOADPF(pf, (CH) + 2);                                 \
    if ((CH) < nchw) {                                                        \
      const unsigned short* bq_ = wcB + 64 * (CH) - 112;                      \
      bw[0] = *(const bf16x8*)(bq_);                                          \
      bw[1] = *(const bf16x8*)(bq_ + 16);                                     \
      bw[2] = *(const bf16x8*)(bq_ + 32);                                     \
      bw[3] = *(const bf16x8*)(bq_ + 48);                                     \
      bw[4] = *(const bf16x8*)(bq_ + 64);                                     \
      bw[5] = *(const bf16x8*)(bq_ + 80);                                     \
      bw[6] = *(const bf16x8*)(bq_ + 96);                                     \
      bw[7] = *(const bf16x8*)(bq_ + 112);                                    \
      __builtin_amdgcn_s_setprio(1);                                          \
      KSTEP0(ABC);                                                            \
      bw[0] = *(const bf16x8*)(bq_ + 128);   /* word 8 */                     \
      bw[1] = *(const bf16x8*)(bq_ + 144);   /* word 9 */                     \
      KSTEP1(ABC);                                                            \
      __builtin_amdgcn_s_setprio(0);                                          \
    }                                                                         \
    asm volatile("s_waitcnt lgkmcnt(0)\n\ts_barrier" ::: "memory");           \
  }

__global__ __launch_bounds__(NTH, 4) void mixer_kernel(
    const float* __restrict__ x, const float* __restrict__ wgt,
    const float* __restrict__ bias, float* __restrict__ out)
{
    __shared__ unsigned short smem[TOT_E] __attribute__((aligned(16)));
    char* ab0 = (char*)smem;                    // A buffer 0 (even chunks)
    char* ab1 = (char*)smem + ABUF_E * 2;       // A buffer 1 (odd chunks)
    unsigned short* wc = smem + WCOP_E;         // 8 shifted reversed-w copies

    const int tid  = threadIdx.x;
    const int lane = tid & 63;
    const int wv   = tid >> 6;                  // 0..7
    const int r    = wv & 3;                    // row oct (32 rows each)
    const int tb   = wv >> 2;                   // tile half: ct = 2j + tb

    // ---- block decode: 512 blocks, adjacent-ct pairs, heavy-first LPT ----
    const int bid  = blockIdx.x;               // 0..511
    const int m    = (bid & 7) + 8 * ((bid >> 3) & 1);
    const int rt   = (bid >> 4) & 3;           // row tile 0..3
    const int j    = 7 - (bid >> 6);           // pair id; j=7 (K=2048) first
    const int nch  = 4 * j + 4;                // shared K sweep chunks (of 64)
    const int nchw = nch - 2 + 2 * tb;         // this wave's MFMA extent

    const float* Xb = x   + (size_t)(m * RPH + rt * BM) * SEQ;
    float*       Ob = out + (size_t)(m * RPH + rt * BM) * SEQ;
    const float* wr = wgt  + m * SEQ;
    const float* br = bias + m * SEQ;

    // ---- staging map: wave stages 16 rows = [32r + 16tb, +16) ----
    const int srow = 32 * r + 16 * tb + (lane >> 2);
    const int colq = lane & 3;                 // 16-fp32 column quarter
    const int wsw  = (srow & 7) << 4;
    const int wb0  = srow * 128 + ((colq * 32) ^ wsw);
    const int wb1  = srow * 128 + ((colq * 32 + 16) ^ wsw);
    const float* Xp = Xb + (size_t)srow * SEQ + colq * 16;

    // ---- issue chunk-0 prefetch immediately (hides under prologue) ----
    PF pf;
    LOADPF(pf, 0);

    // ---- phase 1: reversed bf16 weights into abuf0-alias (256 th) ----
    if (tid < 256) {
        const int t8 = tid * 8;                // 0..2040
        const float* g = wr + (2040 - t8);
        float4 lo = *(const float4*)g;
        float4 hi = *(const float4*)(g + 4);
        uint4 v;
        v.x = f2bf(hi.w) | (f2bf(hi.z) << 16);
        v.y = f2bf(hi.y) | (f2bf(hi.x) << 16);
        v.z = f2bf(lo.w) | (f2bf(lo.z) << 16);
        v.w = f2bf(lo.y) | (f2bf(lo.x) << 16);
        *(uint4*)(smem + 8 + t8) = v;
        if (tid < 21) {                        // guard (8) + pad (160)
            uint4 z = {0u, 0u, 0u, 0u};
            unsigned short* dst = (tid == 0) ? smem
                                 : smem + 8 + 2048 + (tid - 1) * 8;
            *(uint4*)dst = z;
        }
    }
    __syncthreads();

    // ---- phase 2: 8 shifted copies, vectorized: copy_c[i] = wbase[i-c] ----
    #pragma unroll
    for (int c = 0; c < 8; ++c) {
        for (int grp = tid; grp < WSTRIDE / 8; grp += NTH) {
            const int i = grp * 8;
            uint4 g0 = *(const uint4*)(smem + 8 + i - 8);
            uint4 g1 = *(const uint4*)(smem + 8 + i);
            unsigned d[9] = {g0.x, g0.y, g0.z, g0.w,
                             g1.x, g1.y, g1.z, g1.w, 0u};
            const int qd = (16 - 2 * c) >> 2;
            uint4 o;
            if (c & 1) {
                o.x = (d[qd]     >> 16) | (d[qd + 1] << 16);
                o.y = (d[qd + 1] >> 16) | (d[qd + 2] << 16);
                o.z = (d[qd + 2] >> 16) | (d[qd + 3] << 16);
                o.w = (d[qd + 3] >> 16) | (d[qd + 4] << 16);
            } else {
                o.x = d[qd];     o.y = d[qd + 1];
                o.z = d[qd + 2]; o.w = d[qd + 3];
            }
            *(uint4*)(wc + c * WSTRIDE + i) = o;
        }
    }
    __syncthreads();   // wcop ready; wbase alias (ab0) free to overwrite

    // ---- per-lane MFMA constants ----
    const int col_low = lane & 15;
    const int kq      = lane >> 4;
    const int kq16    = kq * 16;
    const int swz     = (col_low & 7) << 4;
    const int rbw     = 32 * r;                // wave's output rows
    const int t0w     = 256 * j + 128 * tb;    // wave's tile col base
    const int cpy     = (col_low + 1) & 7;     // alignment class -> copy id
    const int BcBase  = cpy * WSTRIDE + cpy + 2047 - col_low + 8 * kq;
    const int Arow0   = (rbw      + col_low) * 128;
    const int Arow1   = (rbw + 16 + col_low) * 128;
    const unsigned short* wcB = wc + (BcBase - t0w);

    // ---- seed: stage chunk 0 (shared), advance pf to chunk 1 ----
    WRITEA(ab0, pf);
    LOADPF(pf, 1);
    __syncthreads();                           // ab0(chunk 0) visible to all

    bf16x8 bw[8];
    f32x4 acc[2][8] = {};
    for (int ch = 0; ch < nch; ch += 2) {      // nch always even
        CHUNKBODY(ch,     ab0, ab1);
        CHUNKBODY(ch + 1, ab1, ab0);
    }

    // ---- epilogue: C/D layout col=lane&15, row=(lane>>4)*4+reg ----
    #pragma unroll
    for (int c = 0; c < 8; ++c) {
        const int colg = t0w + 16 * c + col_low;
        const float bv = br[colg];
        #pragma unroll
        for (int a = 0; a < 2; ++a) {
            const int rowl = rbw + 16 * a + 4 * kq;
            #pragma unroll
            for (int rr = 0; rr < 4; ++rr)
                Ob[(size_t)(rowl + rr) * SEQ + colg] = acc[a][c][rr] + bv;
        }
    }
}

extern "C" void kernel_launch(void* const* d_in, const int* in_sizes, int n_in,
                              void* d_out, int out_size, void* d_ws, size_t ws_size,
                              hipStream_t stream) {
    const float* x  = (const float*)d_in[0];
    const float* w  = (const float*)d_in[1];
    const float* bs = (const float*)d_in[2];
    float* out = (float*)d_out;
    dim3 grid(512);    // 16 heads x 4 row tiles x 8 adjacent-ct pairs (LPT)
    dim3 block(NTH);
    hipLaunchKernelGGL(mixer_kernel, grid, block, 0, stream, x, w, bs, out);
}